// Round 1
// baseline (601.644 us; speedup 1.0000x reference)
//
#include <hip/hip_runtime.h>
#include <hip/hip_bf16.h>
#include <stdint.h>

// Problem: y[b,s,o] = sum_d x[b,s,d] * (w_int8[o,d] * scale[o]) + bias[o]
// M = 8192 (B*S), N = 4096 (DOUT), K = 4096 (DIN)
#define MM 8192
#define NN 4096
#define KK 4096
#define BM 128
#define BN 128
#define BK 32

typedef short bf16x8 __attribute__((ext_vector_type(8)));
typedef float f32x4 __attribute__((ext_vector_type(4)));

__device__ __forceinline__ unsigned int f2bf(float f) {
    unsigned int u = __builtin_bit_cast(unsigned int, f);
    u += 0x7FFFu + ((u >> 16) & 1u);   // round-to-nearest-even
    return u >> 16;
}

// x: fp32 [M][K] -> bf16 [M][K].  8 elems / thread.
__global__ __launch_bounds__(256) void cvt_x_kernel(const float* __restrict__ x,
                                                    unsigned short* __restrict__ xb) {
    int i = blockIdx.x * blockDim.x + threadIdx.x;
    const float4* p = (const float4*)x + (size_t)i * 2;
    float4 a = p[0], b = p[1];
    uint4 o;
    o.x = f2bf(a.x) | (f2bf(a.y) << 16);
    o.y = f2bf(a.z) | (f2bf(a.w) << 16);
    o.z = f2bf(b.x) | (f2bf(b.y) << 16);
    o.w = f2bf(b.z) | (f2bf(b.w) << 16);
    ((uint4*)xb)[i] = o;
}

// w: int32 [N][K] (values in [-127,127], exact in bf16) -> bf16 [N][K]. 8/thread.
__global__ __launch_bounds__(256) void cvt_w_kernel(const int* __restrict__ w,
                                                    unsigned short* __restrict__ wb) {
    int i = blockIdx.x * blockDim.x + threadIdx.x;
    const int4* p = (const int4*)w + (size_t)i * 2;
    int4 a = p[0], b = p[1];
    uint4 o;
    o.x = f2bf((float)a.x) | (f2bf((float)a.y) << 16);
    o.y = f2bf((float)a.z) | (f2bf((float)a.w) << 16);
    o.z = f2bf((float)b.x) | (f2bf((float)b.y) << 16);
    o.w = f2bf((float)b.z) | (f2bf((float)b.w) << 16);
    ((uint4*)wb)[i] = o;
}

// C[M][N] = A[M][K] * Bt[N][K]^T, fused epilogue C = acc*scale[n] + bias[n].
// m97 structure: 128x128 tile, BK=32, 4 waves (2x2), global_load_lds width=16,
// single-buffered LDS, 16x16x32 bf16 MFMA, acc 4x4 frags per wave (64x64 out).
__global__ __launch_bounds__(256) void gemm_kernel(const unsigned short* __restrict__ A,
                                                   const unsigned short* __restrict__ Bt,
                                                   const float* __restrict__ scale,
                                                   const float* __restrict__ bias,
                                                   float* __restrict__ C) {
    __shared__ __align__(16) unsigned short As[BM * BK];  // 8 KiB
    __shared__ __align__(16) unsigned short Bs[BN * BK];  // 8 KiB

    const int nbn = NN / BN;              // 32
    const int nwg = (MM / BM) * nbn;      // 2048 (multiple of 8 -> simple swizzle OK)
    const int cpx = nwg >> 3;             // 256 blocks per XCD chunk
    int bid = blockIdx.x;
    int swz = (bid & 7) * cpx + (bid >> 3);
    const int bm = swz / nbn;
    const int bn = swz % nbn;

    const int tid  = threadIdx.x;
    const int lane = tid & 63;
    const int wid  = tid >> 6;     // 0..3
    const int wr   = wid >> 1;     // wave row 0..1 (owns 64 rows)
    const int wc   = wid & 1;      // wave col 0..1 (owns 64 cols)

    const int r  = lane & 15;      // fragment row/col index
    const int kg = lane >> 4;      // k-group 0..3 (8 elems each)

    f32x4 acc[4][4] = {};

    const size_t rowA0 = (size_t)bm * BM;
    const size_t rowB0 = (size_t)bn * BN;

    for (int k0 = 0; k0 < KK; k0 += BK) {
        // ---- stage A,B tiles: 128 rows x 32 bf16 = 8192 B each.
        // slot = 16B chunk index; row = slot>>2, chunk = slot&3.
        // LDS dest is wave-uniform base + lane*16 (linear layout, rule #21).
#pragma unroll
        for (int i = 0; i < 2; ++i) {
            int slot = i * 256 + tid;
            int row  = slot >> 2;
            int ch   = slot & 3;
            const unsigned short* gA = A  + (rowA0 + row) * KK + k0 + ch * 8;
            const unsigned short* gB = Bt + (rowB0 + row) * KK + k0 + ch * 8;
            unsigned short* lA = As + (size_t)(i * 256 + (wid << 6)) * 8;
            unsigned short* lB = Bs + (size_t)(i * 256 + (wid << 6)) * 8;
            __builtin_amdgcn_global_load_lds(
                (const __attribute__((address_space(1))) unsigned int*)gA,
                (__attribute__((address_space(3))) unsigned int*)lA, 16, 0, 0);
            __builtin_amdgcn_global_load_lds(
                (const __attribute__((address_space(1))) unsigned int*)gB,
                (__attribute__((address_space(3))) unsigned int*)lB, 16, 0, 0);
        }
        __syncthreads();

        // ---- LDS -> fragments (8x ds_read_b128) + 16 MFMA
        bf16x8 af[4], bfr[4];
#pragma unroll
        for (int m = 0; m < 4; ++m)
            af[m] = *(const bf16x8*)&As[(wr * 64 + m * 16 + r) * BK + kg * 8];
#pragma unroll
        for (int n = 0; n < 4; ++n)
            bfr[n] = *(const bf16x8*)&Bs[(wc * 64 + n * 16 + r) * BK + kg * 8];
#pragma unroll
        for (int m = 0; m < 4; ++m)
#pragma unroll
            for (int n = 0; n < 4; ++n)
                acc[m][n] = __builtin_amdgcn_mfma_f32_16x16x32_bf16(af[m], bfr[n],
                                                                    acc[m][n], 0, 0, 0);
        __syncthreads();
    }

    // ---- epilogue: C/D layout col=lane&15, row=(lane>>4)*4+j (m89-verified)
    const int rj = lane >> 4;
#pragma unroll
    for (int n = 0; n < 4; ++n) {
        int col  = bn * BN + wc * 64 + n * 16 + r;
        float sc = scale[col];
        float bi = bias[col];
#pragma unroll
        for (int m = 0; m < 4; ++m) {
            int row = bm * BM + wr * 64 + m * 16 + rj * 4;
#pragma unroll
            for (int j = 0; j < 4; ++j) {
                C[(size_t)(row + j) * NN + col] = acc[m][n][j] * sc + bi;
            }
        }
    }
}

extern "C" void kernel_launch(void* const* d_in, const int* in_sizes, int n_in,
                              void* d_out, int out_size, void* d_ws, size_t ws_size,
                              hipStream_t stream) {
    const float* x     = (const float*)d_in[0];
    const int*   w8    = (const int*)d_in[1];     // integer input -> int32 per harness
    const float* scale = (const float*)d_in[2];   // [DOUT]
    const float* bias  = (const float*)d_in[3];   // [DOUT]
    float* out = (float*)d_out;

    unsigned short* xb = (unsigned short*)d_ws;            // bf16 [M][K], 64 MiB
    unsigned short* wb = xb + (size_t)MM * KK;             // bf16 [N][K], 32 MiB

    cvt_x_kernel<<<(MM * KK) / 2048, 256, 0, stream>>>(x, xb);
    cvt_w_kernel<<<(NN * KK) / 2048, 256, 0, stream>>>(w8, wb);
    gemm_kernel<<<(MM / BM) * (NN / BN), 256, 0, stream>>>(xb, wb, scale, bias, out);
}

// Round 3
// 567.102 us; speedup vs baseline: 1.0609x; 1.0609x over previous
//
#include <hip/hip_runtime.h>
#include <stdint.h>

// y[m,n] = sum_k x[m,k] * w8[n,k] * scale[n] + bias[n]
// M=8192, N=4096, K=4096. bf16 MFMA path, fp32 accumulate, fused epilogue.
#define MM 8192
#define NN 4096
#define KK 4096
#define BM 256
#define BN 256
#define BK 64
#define NT (KK / BK)      // 64 K-tiles
#define NHALF (4 * NT)    // 256 half-tiles total

typedef short bf16x8 __attribute__((ext_vector_type(8)));
typedef float f32x4 __attribute__((ext_vector_type(4)));

__device__ __forceinline__ unsigned int f2bf(float f) {
    unsigned int u = __builtin_bit_cast(unsigned int, f);
    u += 0x7FFFu + ((u >> 16) & 1u);   // round-to-nearest-even
    return u >> 16;
}

// x: fp32 [M][K] -> bf16 [M][K]. 8 elems/thread.
__global__ __launch_bounds__(256) void cvt_x_kernel(const float* __restrict__ x,
                                                    unsigned short* __restrict__ xb) {
    int i = blockIdx.x * blockDim.x + threadIdx.x;
    const float4* p = (const float4*)x + (size_t)i * 2;
    float4 a = p[0], b = p[1];
    uint4 o;
    o.x = f2bf(a.x) | (f2bf(a.y) << 16);
    o.y = f2bf(a.z) | (f2bf(a.w) << 16);
    o.z = f2bf(b.x) | (f2bf(b.y) << 16);
    o.w = f2bf(b.z) | (f2bf(b.w) << 16);
    ((uint4*)xb)[i] = o;
}

// w: int32 [N][K] in [-127,127] (exact in bf16) -> bf16 [N][K]. 8/thread.
__global__ __launch_bounds__(256) void cvt_w_kernel(const int* __restrict__ w,
                                                    unsigned short* __restrict__ wb) {
    int i = blockIdx.x * blockDim.x + threadIdx.x;
    const int4* p = (const int4*)w + (size_t)i * 2;
    int4 a = p[0], b = p[1];
    uint4 o;
    o.x = f2bf((float)a.x) | (f2bf((float)a.y) << 16);
    o.y = f2bf((float)a.z) | (f2bf((float)a.w) << 16);
    o.z = f2bf((float)b.x) | (f2bf((float)b.y) << 16);
    o.w = f2bf((float)b.z) | (f2bf((float)b.w) << 16);
    ((uint4*)wb)[i] = o;
}

// LDS byte-offset swizzle: XOR row bits [3:2] (= q bits [10:9]) into byte bits [6:5].
// Involution; preserves 16B alignment. Post-swizzle every ds_read_b128 hits each
// 4-bank group with exactly 8 of 64 lanes -> conflict-free at b128 granularity.
#define SWZ(q) ((q) ^ ((((q) >> 9) & 3) << 5))

// 256x256 8-phase GEMM (m201 template, plain HIP).
// 8 waves (wm 0..1 x wn 0..3). Per-wave output: rows {mh*128 + wm*64 +0..63},
// cols {nh*128 + wn*32 +0..31} -> reads of quadrant (mh,nh) touch ONLY staging
// half (A-half mh, B-half nh). acc[mh*4+i][nh*2+j].
// Halves per K-tile: h0=A-lo h1=B-lo h2=B-hi h3=A-hi (128 rows x 64 = 16 KiB = 2 loads/thread).
// Stream: tile t phase p stages half 4t+7+p = (t+1,h3),(t+2,h0),(t+2,h1),(t+2,h2).
// Safety: region deaths A-lo,B-lo after phase0 barrier; B-hi after phase1; A-hi after
// phase2 (b0/b1/a retained in regs). Boundary vmcnt(6): next tile fully landed,
// 3 next-next halves in flight. vmcnt(0) only at the final boundary.
__global__ __launch_bounds__(512, 2) void gemm_kernel(const unsigned short* __restrict__ A,
                                                      const unsigned short* __restrict__ Bt,
                                                      const float* __restrict__ scale,
                                                      const float* __restrict__ bias,
                                                      float* __restrict__ C) {
    __shared__ __align__(16) unsigned short As[2][BM * BK];  // 64 KiB
    __shared__ __align__(16) unsigned short Bs[2][BN * BK];  // 64 KiB

    const int nbn = NN / BN;                       // 16
    const int cpx = ((MM / BM) * (NN / BN)) >> 3;  // 512/8 = 64 (512 % 8 == 0: bijective)
    int bid = blockIdx.x;
    int swzb = (bid & 7) * cpx + (bid >> 3);
    const int bm = swzb / nbn;
    const int bn = swzb % nbn;

    const int tid  = threadIdx.x;
    const int lane = tid & 63;
    const int wid  = tid >> 6;   // 0..7
    const int wm   = wid >> 2;   // 0..1
    const int wn   = wid & 3;    // 0..3
    const int r    = lane & 15;
    const int kg   = lane >> 4;

    const size_t rowA0 = (size_t)bm * BM;
    const size_t rowB0 = (size_t)bn * BN;

    f32x4 acc[8][4] = {};
    bf16x8 a[4][2], b0[2][2], b1[2][2];

#define STAGE(hid_) do {                                                          \
    int hh = (hid_);                                                              \
    if (hh < NHALF) {                                                             \
        int tt = hh >> 2, h4 = hh & 3;                                            \
        int isA = (h4 == 0) || (h4 == 3);                                         \
        int hi  = (h4 >= 2) ? 1 : 0;                                              \
        int bo  = (tt & 1) * (BM * BK * 2);                                       \
        const unsigned short* gb = isA ? A : Bt;                                  \
        size_t row0 = isA ? rowA0 : rowB0;                                        \
        char* lbase = (isA ? (char*)As : (char*)Bs) + bo + (hi << 14);            \
        _Pragma("unroll")                                                         \
        for (int ii = 0; ii < 2; ++ii) {                                          \
            int q  = (hi << 14) + (ii * 512 + tid) * 16;                          \
            int qs = SWZ(q);                                                      \
            int rw = qs >> 7, cb = qs & 127;                                      \
            const unsigned short* gs = gb + (row0 + rw) * KK + tt * BK + (cb >> 1); \
            char* ld = lbase + (ii * 512 + (wid << 6)) * 16;                      \
            __builtin_amdgcn_global_load_lds(                                     \
                (const __attribute__((address_space(1))) unsigned int*)gs,        \
                (__attribute__((address_space(3))) unsigned int*)ld, 16, 0, 0);   \
        }                                                                         \
    }                                                                             \
} while (0)

// A fragment rows for quadrant mh: mh*128 + wm*64 + i*16 + r  (only A-half mh)
#define READ_A(mh_) do {                                                          \
    _Pragma("unroll")                                                             \
    for (int i_ = 0; i_ < 4; ++i_)                                                \
        _Pragma("unroll")                                                         \
        for (int s_ = 0; s_ < 2; ++s_) {                                          \
            int rw = (mh_) * 128 + wm * 64 + i_ * 16 + r;                         \
            int q  = rw * 128 + s_ * 64 + kg * 16;                                \
            a[i_][s_] = *(const bf16x8*)((char*)As + bufo + SWZ(q));              \
        }                                                                         \
} while (0)

// B fragment rows for quadrant nh: nh*128 + wn*32 + j*16 + r  (only B-half nh)
#define READ_B(nh_, dst_) do {                                                    \
    _Pragma("unroll")                                                             \
    for (int j_ = 0; j_ < 2; ++j_)                                                \
        _Pragma("unroll")                                                         \
        for (int s_ = 0; s_ < 2; ++s_) {                                          \
            int rw = (nh_) * 128 + wn * 32 + j_ * 16 + r;                         \
            int q  = rw * 128 + s_ * 64 + kg * 16;                                \
            dst_[j_][s_] = *(const bf16x8*)((char*)Bs + bufo + SWZ(q));           \
        }                                                                         \
} while (0)

#define MFMA_Q(mh_, nh_, B_) do {                                                 \
    _Pragma("unroll")                                                             \
    for (int i_ = 0; i_ < 4; ++i_)                                                \
        _Pragma("unroll")                                                         \
        for (int j_ = 0; j_ < 2; ++j_)                                            \
            _Pragma("unroll")                                                     \
            for (int s_ = 0; s_ < 2; ++s_)                                        \
                acc[(mh_) * 4 + i_][(nh_) * 2 + j_] =                             \
                    __builtin_amdgcn_mfma_f32_16x16x32_bf16(                      \
                        a[i_][s_], B_[j_][s_], acc[(mh_) * 4 + i_][(nh_) * 2 + j_], 0, 0, 0); \
} while (0)

    // ---- prologue: tile0 fully + tile1 h0..h2 in flight
    STAGE(0); STAGE(1); STAGE(2); STAGE(3);
    asm volatile("s_waitcnt vmcnt(4)");
    STAGE(4); STAGE(5); STAGE(6);
    asm volatile("s_waitcnt vmcnt(6)");
    __builtin_amdgcn_s_barrier();

    for (int t = 0; t < NT; ++t) {
        const int bufo = (t & 1) * (BM * BK * 2);

        // ---- phase 0: read A-lo + B-lo; MFMA Q(0,0); stage (t+1,A-hi)
        READ_A(0);
        READ_B(0, b0);
        STAGE(4 * t + 7);
        asm volatile("s_waitcnt lgkmcnt(8)");
        __builtin_amdgcn_s_barrier();
        asm volatile("s_waitcnt lgkmcnt(0)");
        __builtin_amdgcn_s_setprio(1);
        MFMA_Q(0, 0, b0);
        __builtin_amdgcn_s_setprio(0);
        __builtin_amdgcn_s_barrier();

        // ---- phase 1: read B-hi; MFMA Q(0,1); stage (t+2,A-lo) [A-lo dead]
        READ_B(1, b1);
        STAGE(4 * t + 8);
        __builtin_amdgcn_s_barrier();
        asm volatile("s_waitcnt lgkmcnt(0)");
        __builtin_amdgcn_s_setprio(1);
        MFMA_Q(0, 1, b1);
        __builtin_amdgcn_s_setprio(0);
        __builtin_amdgcn_s_barrier();

        // ---- phase 2: read A-hi; MFMA Q(1,1) (b1 in regs); stage (t+2,B-lo) [dead]
        READ_A(1);
        STAGE(4 * t + 9);
        __builtin_amdgcn_s_barrier();
        asm volatile("s_waitcnt lgkmcnt(0)");
        __builtin_amdgcn_s_setprio(1);
        MFMA_Q(1, 1, b1);
        __builtin_amdgcn_s_setprio(0);
        __builtin_amdgcn_s_barrier();

        // ---- phase 3: MFMA Q(1,0) (a, b0 in regs); stage (t+2,B-hi) [dead]; boundary
        STAGE(4 * t + 10);
        __builtin_amdgcn_s_barrier();
        __builtin_amdgcn_s_setprio(1);
        MFMA_Q(1, 0, b0);
        __builtin_amdgcn_s_setprio(0);
        if (t < NT - 1) {
            if (t == NT - 2) asm volatile("s_waitcnt vmcnt(0)");
            else             asm volatile("s_waitcnt vmcnt(6)");
            __builtin_amdgcn_s_barrier();
        }
    }

    // ---- epilogue: C/D layout col=lane&15, row=(lane>>4)*4+j (m89-verified)
    const int rj = lane >> 4;
#pragma unroll
    for (int nj = 0; nj < 4; ++nj) {
        int col  = bn * BN + (nj >> 1) * 128 + wn * 32 + (nj & 1) * 16 + r;
        float sc = scale[col];
        float bi = bias[col];
#pragma unroll
        for (int mi = 0; mi < 8; ++mi) {
            int row = bm * BM + (mi >> 2) * 128 + wm * 64 + (mi & 3) * 16 + rj * 4;
#pragma unroll
            for (int j = 0; j < 4; ++j) {
                C[(size_t)(row + j) * NN + col] = acc[mi][nj][j] * sc + bi;
            }
        }
    }
#undef STAGE
#undef READ_A
#undef READ_B
#undef MFMA_Q
}

extern "C" void kernel_launch(void* const* d_in, const int* in_sizes, int n_in,
                              void* d_out, int out_size, void* d_ws, size_t ws_size,
                              hipStream_t stream) {
    const float* x     = (const float*)d_in[0];
    const int*   w8    = (const int*)d_in[1];
    const float* scale = (const float*)d_in[2];
    const float* bias  = (const float*)d_in[3];
    float* out = (float*)d_out;

    unsigned short* xb = (unsigned short*)d_ws;        // bf16 [M][K], 64 MiB
    unsigned short* wb = xb + (size_t)MM * KK;         // bf16 [N][K], 32 MiB

    cvt_x_kernel<<<(MM * KK) / 2048, 256, 0, stream>>>(x, xb);
    cvt_w_kernel<<<(NN * KK) / 2048, 256, 0, stream>>>(w8, wb);
    gemm_kernel<<<(MM / BM) * (NN / BN), 512, 0, stream>>>(xb, wb, scale, bias, out);
}

// Round 4
// 540.906 us; speedup vs baseline: 1.1123x; 1.0484x over previous
//
#include <hip/hip_runtime.h>
#include <stdint.h>

// y[m,n] = sum_k x[m,k] * w8[n,k] * scale[n] + bias[n]
// M=8192, N=4096, K=4096. bf16 MFMA path, fp32 accumulate, fused epilogue.
#define MM 8192
#define NN 4096
#define KK 4096
#define BM 256
#define BN 256
#define BK 64
#define NT (KK / BK)      // 64 K-tiles
#define NHALF (4 * NT)    // 256 half-tiles total

typedef short bf16x8 __attribute__((ext_vector_type(8)));
typedef float f32x4 __attribute__((ext_vector_type(4)));

__device__ __forceinline__ unsigned int f2bf(float f) {
    unsigned int u = __builtin_bit_cast(unsigned int, f);
    u += 0x7FFFu + ((u >> 16) & 1u);   // round-to-nearest-even
    return u >> 16;
}

// x: fp32 [M][K] -> bf16 [M][K]. 8 elems/thread.
__global__ __launch_bounds__(256) void cvt_x_kernel(const float* __restrict__ x,
                                                    unsigned short* __restrict__ xb) {
    int i = blockIdx.x * blockDim.x + threadIdx.x;
    const float4* p = (const float4*)x + (size_t)i * 2;
    float4 a = p[0], b = p[1];
    uint4 o;
    o.x = f2bf(a.x) | (f2bf(a.y) << 16);
    o.y = f2bf(a.z) | (f2bf(a.w) << 16);
    o.z = f2bf(b.x) | (f2bf(b.y) << 16);
    o.w = f2bf(b.z) | (f2bf(b.w) << 16);
    ((uint4*)xb)[i] = o;
}

// w: int32 [N][K] in [-127,127] (exact in bf16) -> bf16 [N][K]. 8/thread.
__global__ __launch_bounds__(256) void cvt_w_kernel(const int* __restrict__ w,
                                                    unsigned short* __restrict__ wb) {
    int i = blockIdx.x * blockDim.x + threadIdx.x;
    const int4* p = (const int4*)w + (size_t)i * 2;
    int4 a = p[0], b = p[1];
    uint4 o;
    o.x = f2bf((float)a.x) | (f2bf((float)a.y) << 16);
    o.y = f2bf((float)a.z) | (f2bf((float)a.w) << 16);
    o.z = f2bf((float)b.x) | (f2bf((float)b.y) << 16);
    o.w = f2bf((float)b.z) | (f2bf((float)b.w) << 16);
    ((uint4*)wb)[i] = o;
}

// LDS byte-offset swizzle (v2): XOR row bits [2:0] (= q bits [10:8]) into the 16B-slot
// index (byte bits [6:4]). For every ds_read_b128 quarter-wave (16 lanes = 16 distinct
// rows, same column slot), slot ^= (row>>1)&7 covers all 8 slots exactly twice ->
// all 32 banks, 2 lanes/bank-group (free). Involution; preserves 16B alignment;
// row bits untouched.
#define SWZ(q) ((q) ^ ((((q) >> 8) & 7) << 4))

// 256x256 8-phase GEMM (m201 template, plain HIP).
// 8 waves (wm 0..1 x wn 0..3). Per-wave output: rows {mh*128 + wm*64 +0..63},
// cols {nh*128 + wn*32 +0..31} -> reads of quadrant (mh,nh) touch ONLY staging
// half (A-half mh, B-half nh). acc[mh*4+i][nh*2+j].
// Halves per K-tile: h0=A-lo h1=B-lo h2=B-hi h3=A-hi (128 rows x 64 = 16 KiB = 2 loads/thread).
// Stream: tile t phase p stages half 4t+7+p = (t+1,h3),(t+2,h0),(t+2,h1),(t+2,h2).
// Safety: region deaths A-lo,B-lo after phase0 barrier; B-hi after phase1; A-hi after
// phase2 (b0/b1/a retained in regs). Boundary vmcnt(6): next tile fully landed,
// 3 next-next halves in flight. vmcnt(0) only at the final boundary.
__global__ __launch_bounds__(512, 2) void gemm_kernel(const unsigned short* __restrict__ A,
                                                      const unsigned short* __restrict__ Bt,
                                                      const float* __restrict__ scale,
                                                      const float* __restrict__ bias,
                                                      float* __restrict__ C) {
    __shared__ __align__(16) unsigned short As[2][BM * BK];  // 64 KiB
    __shared__ __align__(16) unsigned short Bs[2][BN * BK];  // 64 KiB

    const int nbn = NN / BN;                       // 16
    const int cpx = ((MM / BM) * (NN / BN)) >> 3;  // 512/8 = 64 (512 % 8 == 0: bijective)
    int bid = blockIdx.x;
    int swzb = (bid & 7) * cpx + (bid >> 3);
    const int bm = swzb / nbn;
    const int bn = swzb % nbn;

    const int tid  = threadIdx.x;
    const int lane = tid & 63;
    const int wid  = tid >> 6;   // 0..7
    const int wm   = wid >> 2;   // 0..1
    const int wn   = wid & 3;    // 0..3
    const int r    = lane & 15;
    const int kg   = lane >> 4;

    const size_t rowA0 = (size_t)bm * BM;
    const size_t rowB0 = (size_t)bn * BN;

    f32x4 acc[8][4] = {};
    bf16x8 a[4][2], b0[2][2], b1[2][2];

#define STAGE(hid_) do {                                                          \
    int hh = (hid_);                                                              \
    if (hh < NHALF) {                                                             \
        int tt = hh >> 2, h4 = hh & 3;                                            \
        int isA = (h4 == 0) || (h4 == 3);                                         \
        int hi  = (h4 >= 2) ? 1 : 0;                                              \
        int bo  = (tt & 1) * (BM * BK * 2);                                       \
        const unsigned short* gb = isA ? A : Bt;                                  \
        size_t row0 = isA ? rowA0 : rowB0;                                        \
        char* lbase = (isA ? (char*)As : (char*)Bs) + bo + (hi << 14);            \
        _Pragma("unroll")                                                         \
        for (int ii = 0; ii < 2; ++ii) {                                          \
            int q  = (hi << 14) + (ii * 512 + tid) * 16;                          \
            int qs = SWZ(q);                                                      \
            int rw = qs >> 7, cb = qs & 127;                                      \
            const unsigned short* gs = gb + (row0 + rw) * KK + tt * BK + (cb >> 1); \
            char* ld = lbase + (ii * 512 + (wid << 6)) * 16;                      \
            __builtin_amdgcn_global_load_lds(                                     \
                (const __attribute__((address_space(1))) unsigned int*)gs,        \
                (__attribute__((address_space(3))) unsigned int*)ld, 16, 0, 0);   \
        }                                                                         \
    }                                                                             \
} while (0)

// A fragment rows for quadrant mh: mh*128 + wm*64 + i*16 + r  (only A-half mh)
#define READ_A(mh_) do {                                                          \
    _Pragma("unroll")                                                             \
    for (int i_ = 0; i_ < 4; ++i_)                                                \
        _Pragma("unroll")                                                         \
        for (int s_ = 0; s_ < 2; ++s_) {                                          \
            int rw = (mh_) * 128 + wm * 64 + i_ * 16 + r;                         \
            int q  = rw * 128 + s_ * 64 + kg * 16;                                \
            a[i_][s_] = *(const bf16x8*)((char*)As + bufo + SWZ(q));              \
        }                                                                         \
} while (0)

// B fragment rows for quadrant nh: nh*128 + wn*32 + j*16 + r  (only B-half nh)
#define READ_B(nh_, dst_) do {                                                    \
    _Pragma("unroll")                                                             \
    for (int j_ = 0; j_ < 2; ++j_)                                                \
        _Pragma("unroll")                                                         \
        for (int s_ = 0; s_ < 2; ++s_) {                                          \
            int rw = (nh_) * 128 + wn * 32 + j_ * 16 + r;                         \
            int q  = rw * 128 + s_ * 64 + kg * 16;                                \
            dst_[j_][s_] = *(const bf16x8*)((char*)Bs + bufo + SWZ(q));           \
        }                                                                         \
} while (0)

#define MFMA_Q(mh_, nh_, B_) do {                                                 \
    _Pragma("unroll")                                                             \
    for (int i_ = 0; i_ < 4; ++i_)                                                \
        _Pragma("unroll")                                                         \
        for (int j_ = 0; j_ < 2; ++j_)                                            \
            _Pragma("unroll")                                                     \
            for (int s_ = 0; s_ < 2; ++s_)                                        \
                acc[(mh_) * 4 + i_][(nh_) * 2 + j_] =                             \
                    __builtin_amdgcn_mfma_f32_16x16x32_bf16(                      \
                        a[i_][s_], B_[j_][s_], acc[(mh_) * 4 + i_][(nh_) * 2 + j_], 0, 0, 0); \
} while (0)

    // ---- prologue: tile0 fully + tile1 h0..h2 in flight
    STAGE(0); STAGE(1); STAGE(2); STAGE(3);
    asm volatile("s_waitcnt vmcnt(4)");
    STAGE(4); STAGE(5); STAGE(6);
    asm volatile("s_waitcnt vmcnt(6)");
    __builtin_amdgcn_s_barrier();

    for (int t = 0; t < NT; ++t) {
        const int bufo = (t & 1) * (BM * BK * 2);

        // ---- phase 0: read A-lo + B-lo; MFMA Q(0,0); stage (t+1,A-hi)
        READ_A(0);
        READ_B(0, b0);
        STAGE(4 * t + 7);
        asm volatile("s_waitcnt lgkmcnt(8)");
        __builtin_amdgcn_s_barrier();
        asm volatile("s_waitcnt lgkmcnt(0)");
        __builtin_amdgcn_s_setprio(1);
        MFMA_Q(0, 0, b0);
        __builtin_amdgcn_s_setprio(0);
        __builtin_amdgcn_s_barrier();

        // ---- phase 1: read B-hi; MFMA Q(0,1); stage (t+2,A-lo) [A-lo dead]
        READ_B(1, b1);
        STAGE(4 * t + 8);
        __builtin_amdgcn_s_barrier();
        asm volatile("s_waitcnt lgkmcnt(0)");
        __builtin_amdgcn_s_setprio(1);
        MFMA_Q(0, 1, b1);
        __builtin_amdgcn_s_setprio(0);
        __builtin_amdgcn_s_barrier();

        // ---- phase 2: read A-hi; MFMA Q(1,1) (b1 in regs); stage (t+2,B-lo) [dead]
        READ_A(1);
        STAGE(4 * t + 9);
        __builtin_amdgcn_s_barrier();
        asm volatile("s_waitcnt lgkmcnt(0)");
        __builtin_amdgcn_s_setprio(1);
        MFMA_Q(1, 1, b1);
        __builtin_amdgcn_s_setprio(0);
        __builtin_amdgcn_s_barrier();

        // ---- phase 3: MFMA Q(1,0) (a, b0 in regs); stage (t+2,B-hi) [dead]; boundary
        STAGE(4 * t + 10);
        __builtin_amdgcn_s_barrier();
        __builtin_amdgcn_s_setprio(1);
        MFMA_Q(1, 0, b0);
        __builtin_amdgcn_s_setprio(0);
        if (t < NT - 1) {
            if (t == NT - 2) asm volatile("s_waitcnt vmcnt(0)");
            else             asm volatile("s_waitcnt vmcnt(6)");
            __builtin_amdgcn_s_barrier();
        }
    }

    // ---- epilogue: C/D layout col=lane&15, row=(lane>>4)*4+j (m89-verified)
    const int rj = lane >> 4;
#pragma unroll
    for (int nj = 0; nj < 4; ++nj) {
        int col  = bn * BN + (nj >> 1) * 128 + wn * 32 + (nj & 1) * 16 + r;
        float sc = scale[col];
        float bi = bias[col];
#pragma unroll
        for (int mi = 0; mi < 8; ++mi) {
            int row = bm * BM + (mi >> 2) * 128 + wm * 64 + (mi & 3) * 16 + rj * 4;
#pragma unroll
            for (int j = 0; j < 4; ++j) {
                C[(size_t)(row + j) * NN + col] = acc[mi][nj][j] * sc + bi;
            }
        }
    }
#undef STAGE
#undef READ_A
#undef READ_B
#undef MFMA_Q
}

extern "C" void kernel_launch(void* const* d_in, const int* in_sizes, int n_in,
                              void* d_out, int out_size, void* d_ws, size_t ws_size,
                              hipStream_t stream) {
    const float* x     = (const float*)d_in[0];
    const int*   w8    = (const int*)d_in[1];
    const float* scale = (const float*)d_in[2];
    const float* bias  = (const float*)d_in[3];
    float* out = (float*)d_out;

    unsigned short* xb = (unsigned short*)d_ws;        // bf16 [M][K], 64 MiB
    unsigned short* wb = xb + (size_t)MM * KK;         // bf16 [N][K], 32 MiB

    cvt_x_kernel<<<(MM * KK) / 2048, 256, 0, stream>>>(x, xb);
    cvt_w_kernel<<<(NN * KK) / 2048, 256, 0, stream>>>(w8, wb);
    gemm_kernel<<<(MM / BM) * (NN / BN), 512, 0, stream>>>(xb, wb, scale, bias, out);
}

// Round 5
// 524.953 us; speedup vs baseline: 1.1461x; 1.0304x over previous
//
#include <hip/hip_runtime.h>
#include <stdint.h>

// y[m,n] = sum_k x[m,k] * w8[n,k] * scale[n] + bias[n]
// M=8192, N=4096, K=4096. bf16 MFMA path, fp32 accumulate, fused epilogue.
#define MM 8192
#define NN 4096
#define KK 4096
#define BM 256
#define BN 256
#define BK 64
#define NT (KK / BK)      // 64 K-tiles

typedef short bf16x8 __attribute__((ext_vector_type(8)));
typedef float f32x4 __attribute__((ext_vector_type(4)));

__device__ __forceinline__ unsigned int f2bf(float f) {
    unsigned int u = __builtin_bit_cast(unsigned int, f);
    u += 0x7FFFu + ((u >> 16) & 1u);   // round-to-nearest-even
    return u >> 16;
}

// Fused conversion, fully coalesced: 16 B/lane loads, 8 B/lane stores, grid-stride.
// Region 0: x fp32->bf16 (MM*KK); region 1: w int32->bf16 (NN*KK, exact for |w|<=127).
__global__ __launch_bounds__(256) void cvt_kernel(const float* __restrict__ x,
                                                  const int* __restrict__ w,
                                                  unsigned short* __restrict__ xb,
                                                  unsigned short* __restrict__ wb) {
    const int stride = gridDim.x * blockDim.x;
    const int tid0 = blockIdx.x * blockDim.x + threadIdx.x;
    const int nx = MM * KK / 4;
    for (int i = tid0; i < nx; i += stride) {
        float4 v = ((const float4*)x)[i];
        uint2 o;
        o.x = f2bf(v.x) | (f2bf(v.y) << 16);
        o.y = f2bf(v.z) | (f2bf(v.w) << 16);
        ((uint2*)xb)[i] = o;
    }
    const int nw = NN * KK / 4;
    for (int i = tid0; i < nw; i += stride) {
        int4 v = ((const int4*)w)[i];
        uint2 o;
        o.x = f2bf((float)v.x) | (f2bf((float)v.y) << 16);
        o.y = f2bf((float)v.z) | (f2bf((float)v.w) << 16);
        ((uint2*)wb)[i] = o;
    }
}

// LDS byte-offset swizzle: q ^ (((q>>8)&7)<<4). For all read addresses used below this
// equals q ^ ((r>>1)<<4) (r = lane&15): compile-time fields (mh,i,s,bufo) occupy disjoint
// bits and don't leak into the XOR source -> read addr = runtime_base + compile_imm.
#define SWZ(q) ((q) ^ ((((q) >> 8) & 7) << 4))

// 256x256 8-phase GEMM (m201 template). Schedule identical to round 4 (verified, 0 bank
// conflicts); this round only removes steady-state VALU: precomputed swizzled LDS offsets
// (HK technique #8) + K-loop unrolled x2 for compile-time buffer parity.
__global__ __launch_bounds__(512, 2) void gemm_kernel(const unsigned short* __restrict__ A,
                                                      const unsigned short* __restrict__ Bt,
                                                      const float* __restrict__ scale,
                                                      const float* __restrict__ bias,
                                                      float* __restrict__ C) {
    __shared__ __align__(16) unsigned short As[2][BM * BK];  // 64 KiB
    __shared__ __align__(16) unsigned short Bs[2][BN * BK];  // 64 KiB

    const int nbn = NN / BN;                       // 16
    const int cpx = ((MM / BM) * (NN / BN)) >> 3;  // 64 (512 % 8 == 0: bijective)
    int bid = blockIdx.x;
    int swzb = (bid & 7) * cpx + (bid >> 3);
    const int bm = swzb / nbn;
    const int bn = swzb % nbn;

    const int tid  = threadIdx.x;
    const int lane = tid & 63;
    const int wid  = tid >> 6;   // 0..7
    const int wm   = wid >> 2;   // 0..1
    const int wn   = wid & 3;    // 0..3
    const int r    = lane & 15;
    const int kg   = lane >> 4;

    const int rowA0 = bm * BM;
    const int rowB0 = bn * BN;

    // ---- precomputed swizzled LDS read bases (runtime part; all else is imm)
    const int rt0   = (r * 128 + kg * 16) ^ ((r >> 1) << 4);
    const int offA0 = wm * 8192 + rt0;
    const int offA1 = offA0 ^ 64;
    const int offB0 = wn * 4096 + rt0;
    const int offB1 = offB0 ^ 64;
    char* Ab = (char*)As;
    char* Bb = (char*)Bs;

    // ---- precomputed stage offsets: per half (hi) and chunk (ii).
    // global byte offset excl. tt*128; LDS byte offset excl. buffer parity.
    int goA[2][2], goB[2][2], lo[2][2];
#pragma unroll
    for (int hi = 0; hi < 2; ++hi)
#pragma unroll
        for (int ii = 0; ii < 2; ++ii) {
            int q  = (hi << 14) + (ii * 512 + tid) * 16;
            int qs = SWZ(q);
            int rw = qs >> 7, cb = qs & 127;
            goA[hi][ii] = (rowA0 + rw) * (KK * 2) + cb;
            goB[hi][ii] = (rowB0 + rw) * (KK * 2) + cb;
            lo[hi][ii]  = (hi << 14) + ii * 8192 + wid * 1024;
        }

    f32x4 acc[8][4] = {};
    bf16x8 a[4][2], b0[2][2], b1[2][2];

#define STAGE_A(hi_, tt_, BUFO_) do {                                             \
    if ((tt_) < NT) {                                                             \
        _Pragma("unroll")                                                         \
        for (int ii = 0; ii < 2; ++ii) {                                          \
            const char* gs = (const char*)A + goA[hi_][ii] + (tt_) * 128;         \
            char* ld = Ab + (BUFO_) + lo[hi_][ii];                                \
            __builtin_amdgcn_global_load_lds(                                     \
                (const __attribute__((address_space(1))) unsigned int*)gs,        \
                (__attribute__((address_space(3))) unsigned int*)ld, 16, 0, 0);   \
        }                                                                         \
    }                                                                             \
} while (0)

#define STAGE_B(hi_, tt_, BUFO_) do {                                             \
    if ((tt_) < NT) {                                                             \
        _Pragma("unroll")                                                         \
        for (int ii = 0; ii < 2; ++ii) {                                          \
            const char* gs = (const char*)Bt + goB[hi_][ii] + (tt_) * 128;        \
            char* ld = Bb + (BUFO_) + lo[hi_][ii];                                \
            __builtin_amdgcn_global_load_lds(                                     \
                (const __attribute__((address_space(1))) unsigned int*)gs,        \
                (__attribute__((address_space(3))) unsigned int*)ld, 16, 0, 0);   \
        }                                                                         \
    }                                                                             \
} while (0)

#define READ_A(mh_, BUFO_) do {                                                   \
    _Pragma("unroll")                                                             \
    for (int i_ = 0; i_ < 4; ++i_) {                                              \
        a[i_][0] = *(const bf16x8*)(Ab + (BUFO_) + (mh_) * 16384 + i_ * 2048 + offA0); \
        a[i_][1] = *(const bf16x8*)(Ab + (BUFO_) + (mh_) * 16384 + i_ * 2048 + offA1); \
    }                                                                             \
} while (0)

#define READ_B(nh_, dst_, BUFO_) do {                                             \
    _Pragma("unroll")                                                             \
    for (int j_ = 0; j_ < 2; ++j_) {                                              \
        dst_[j_][0] = *(const bf16x8*)(Bb + (BUFO_) + (nh_) * 16384 + j_ * 2048 + offB0); \
        dst_[j_][1] = *(const bf16x8*)(Bb + (BUFO_) + (nh_) * 16384 + j_ * 2048 + offB1); \
    }                                                                             \
} while (0)

// s-outer: 8 independent MFMAs before the dependent second half.
#define MFMA_Q(mh_, nh_, B_) do {                                                 \
    _Pragma("unroll")                                                             \
    for (int s_ = 0; s_ < 2; ++s_)                                                \
        _Pragma("unroll")                                                         \
        for (int i_ = 0; i_ < 4; ++i_)                                            \
            _Pragma("unroll")                                                     \
            for (int j_ = 0; j_ < 2; ++j_)                                        \
                acc[(mh_) * 4 + i_][(nh_) * 2 + j_] =                             \
                    __builtin_amdgcn_mfma_f32_16x16x32_bf16(                      \
                        a[i_][s_], B_[j_][s_], acc[(mh_) * 4 + i_][(nh_) * 2 + j_], 0, 0, 0); \
} while (0)

// One K-tile, 4 phases. Stages: ph0 -> (t+1, A-hi) other parity; ph1..3 -> (t+2,
// A-lo/B-lo/B-hi) same parity (regions dead per round-2/3 analysis, verified).
#define KTILE(t_, BUFO_, OTHER_) do {                                             \
    READ_A(0, BUFO_);                                                             \
    READ_B(0, b0, BUFO_);                                                         \
    STAGE_A(1, (t_) + 1, OTHER_);                                                 \
    asm volatile("s_waitcnt lgkmcnt(8)");                                         \
    __builtin_amdgcn_s_barrier();                                                 \
    asm volatile("s_waitcnt lgkmcnt(0)");                                         \
    __builtin_amdgcn_s_setprio(1); MFMA_Q(0, 0, b0); __builtin_amdgcn_s_setprio(0); \
    __builtin_amdgcn_s_barrier();                                                 \
    READ_B(1, b1, BUFO_);                                                         \
    STAGE_A(0, (t_) + 2, BUFO_);                                                  \
    __builtin_amdgcn_s_barrier();                                                 \
    asm volatile("s_waitcnt lgkmcnt(0)");                                         \
    __builtin_amdgcn_s_setprio(1); MFMA_Q(0, 1, b1); __builtin_amdgcn_s_setprio(0); \
    __builtin_amdgcn_s_barrier();                                                 \
    READ_A(1, BUFO_);                                                             \
    STAGE_B(0, (t_) + 2, BUFO_);                                                  \
    __builtin_amdgcn_s_barrier();                                                 \
    asm volatile("s_waitcnt lgkmcnt(0)");                                         \
    __builtin_amdgcn_s_setprio(1); MFMA_Q(1, 1, b1); __builtin_amdgcn_s_setprio(0); \
    __builtin_amdgcn_s_barrier();                                                 \
    STAGE_B(1, (t_) + 2, BUFO_);                                                  \
    __builtin_amdgcn_s_barrier();                                                 \
    __builtin_amdgcn_s_setprio(1); MFMA_Q(1, 0, b0); __builtin_amdgcn_s_setprio(0); \
    if ((t_) < NT - 1) {                                                          \
        if ((t_) == NT - 2) asm volatile("s_waitcnt vmcnt(0)");                   \
        else                asm volatile("s_waitcnt vmcnt(6)");                   \
        __builtin_amdgcn_s_barrier();                                             \
    }                                                                             \
} while (0)

    // ---- prologue: tile0 (h0..h3) + tile1 (h0..h2) in flight (order preserved)
    STAGE_A(0, 0, 0);       // h0 A-lo t0
    STAGE_B(0, 0, 0);       // h1 B-lo t0
    STAGE_B(1, 0, 0);       // h2 B-hi t0
    STAGE_A(1, 0, 0);       // h3 A-hi t0
    asm volatile("s_waitcnt vmcnt(4)");
    STAGE_A(0, 1, 0x8000);  // h0 A-lo t1
    STAGE_B(0, 1, 0x8000);  // h1 B-lo t1
    STAGE_B(1, 1, 0x8000);  // h2 B-hi t1
    asm volatile("s_waitcnt vmcnt(6)");
    __builtin_amdgcn_s_barrier();

    for (int t2 = 0; t2 < NT; t2 += 2) {
        KTILE(t2,     0,      0x8000);
        KTILE(t2 + 1, 0x8000, 0);
    }

    // ---- epilogue: C/D layout col=lane&15, row=(lane>>4)*4+j (m89-verified)
    const int rj = lane >> 4;
#pragma unroll
    for (int nj = 0; nj < 4; ++nj) {
        int col  = bn * BN + (nj >> 1) * 128 + wn * 32 + (nj & 1) * 16 + r;
        float sc = scale[col];
        float bi = bias[col];
#pragma unroll
        for (int mi = 0; mi < 8; ++mi) {
            int row = bm * BM + (mi >> 2) * 128 + wm * 64 + (mi & 3) * 16 + rj * 4;
#pragma unroll
            for (int j = 0; j < 4; ++j) {
                C[(size_t)(row + j) * NN + col] = acc[mi][nj][j] * sc + bi;
            }
        }
    }
#undef STAGE_A
#undef STAGE_B
#undef READ_A
#undef READ_B
#undef MFMA_Q
#undef KTILE
}

extern "C" void kernel_launch(void* const* d_in, const int* in_sizes, int n_in,
                              void* d_out, int out_size, void* d_ws, size_t ws_size,
                              hipStream_t stream) {
    const float* x     = (const float*)d_in[0];
    const int*   w8    = (const int*)d_in[1];
    const float* scale = (const float*)d_in[2];
    const float* bias  = (const float*)d_in[3];
    float* out = (float*)d_out;

    unsigned short* xb = (unsigned short*)d_ws;        // bf16 [M][K], 64 MiB
    unsigned short* wb = xb + (size_t)MM * KK;         // bf16 [N][K], 32 MiB

    cvt_kernel<<<8192, 256, 0, stream>>>(x, w8, xb, wb);
    gemm_kernel<<<(MM / BM) * (NN / BN), 512, 0, stream>>>(xb, wb, scale, bias, out);
}